// Round 6
// baseline (62.536 us; speedup 1.0000x reference)
//
#include <hip/hip_runtime.h>
#include <string.h>

#define AA (-0.75f)

__device__ __forceinline__ float k1f(float x) {
    return ((AA + 2.0f) * x - (AA + 3.0f)) * x * x + 1.0f;
}
__device__ __forceinline__ float k2f(float x) {
    return ((AA * x - 5.0f * AA) * x + 8.0f * AA) * x - 4.0f * AA;
}

__device__ __forceinline__ int reflect_clip(int idx, int size) {
    int span = size - 1;
    int i = idx < 0 ? -idx : idx;
    i = i % (2 * span);
    if (i > span) i = 2 * span - i;
    return i;
}

// LDS bank swizzle: logical element a -> a ^ ((a>>5)&31). Bijective per row.
__device__ __forceinline__ int swz(int a) { return a ^ ((a >> 5) & 31); }

struct alignas(16) Tap { int4 i; float4 w; };   // 32 B

// ---------------- tap-table pre-kernel ----------------
// 16384 threads: [0,8192) = y entries (row offsets premultiplied by W),
// [8192,16384) = x entries (swizzled LDS indices).
__global__ __launch_bounds__(256)
void tap_kernel(const float* __restrict__ rate,
                const float* __restrict__ center,
                Tap* __restrict__ ytab, Tap* __restrict__ xtab)
{
    constexpr int HW = 512;
    const int idx = blockIdx.x * 256 + threadIdx.x;
    const bool isY = idx < 8192;
    const int e = isY ? idx : idx - 8192;
    const int b = e >> 9;
    const int q = e & 511;

    const float r  = rate[b];
    const float cx = center[2 * b + 0];
    const float cy = center[2 * b + 1];
    const float c  = isY ? cy : cx;

    const float g = 0.00390625f * (float)q - 1.0f;
    const float G = (g - c) / r + c;
    const float i = (G + 1.0f) * 0.5f * 511.0f;
    const float f0 = floorf(i);
    const float tt = i - f0;
    const int   i0 = (int)f0;

    Tap t;
    t.w = make_float4(k2f(tt + 1.0f), k1f(tt), k1f(1.0f - tt), k2f(2.0f - tt));
    const int j0 = reflect_clip(i0 - 1, HW);
    const int j1 = reflect_clip(i0    , HW);
    const int j2 = reflect_clip(i0 + 1, HW);
    const int j3 = reflect_clip(i0 + 2, HW);
    if (isY) {
        t.i = make_int4(j0 * HW, j1 * HW, j2 * HW, j3 * HW);
        ytab[e] = t;
    } else {
        t.i = make_int4(swz(j0), swz(j1), swz(j2), swz(j3));
        xtab[e] = t;
    }
}

// ---------------- main kernel (table-driven taps) ----------------
__global__ __launch_bounds__(256, 4)
void pds6_kernel(const float* __restrict__ x,
                 const Tap* __restrict__ ytab,
                 const Tap* __restrict__ xtab,
                 float* __restrict__ out)
{
    constexpr int C = 8, H = 512, W = 512;

    // XCD-chunked remap (8192 % 8 == 0 -> bijective).
    const int orig = blockIdx.x;
    const int id = (orig & 7) * 1024 + (orig >> 3);
    const int b = id >> 9;
    const int h = id & (H - 1);
    const int t = threadIdx.x;

    // ---- y taps: one uniform 32B entry ----
    const Tap yt = ytab[id];
    const int ro0 = yt.i.x, ro1 = yt.i.y, ro2 = yt.i.z, ro3 = yt.i.w;
    const float wy0 = yt.w.x, wy1 = yt.w.y, wy2 = yt.w.z, wy3 = yt.w.w;

    // ---- issue all 16 row loads ----
    const float* imgb = x + (size_t)b * C * H * W;
    const int cc4 = (t & 127) << 2;
    const int ch0 = (t >> 7);
    const float* base0 = imgb + (size_t)(ch0 + 0) * (H * W) + cc4;
    const float* base1 = imgb + (size_t)(ch0 + 2) * (H * W) + cc4;
    const float* base2 = imgb + (size_t)(ch0 + 4) * (H * W) + cc4;
    const float* base3 = imgb + (size_t)(ch0 + 6) * (H * W) + cc4;

    float4 p00 = *(const float4*)(base0 + ro0);
    float4 p01 = *(const float4*)(base0 + ro1);
    float4 p02 = *(const float4*)(base0 + ro2);
    float4 p03 = *(const float4*)(base0 + ro3);
    float4 p10 = *(const float4*)(base1 + ro0);
    float4 p11 = *(const float4*)(base1 + ro1);
    float4 p12 = *(const float4*)(base1 + ro2);
    float4 p13 = *(const float4*)(base1 + ro3);
    float4 p20 = *(const float4*)(base2 + ro0);
    float4 p21 = *(const float4*)(base2 + ro1);
    float4 p22 = *(const float4*)(base2 + ro2);
    float4 p23 = *(const float4*)(base2 + ro3);
    float4 p30 = *(const float4*)(base3 + ro0);
    float4 p31 = *(const float4*)(base3 + ro1);
    float4 p32 = *(const float4*)(base3 + ro2);
    float4 p33 = *(const float4*)(base3 + ro3);

    // ---- x taps: two 32B entries per thread (cache-hot table) ----
    const Tap ta = xtab[(b << 9) + 2 * t];
    const Tap tb = xtab[(b << 9) + 2 * t + 1];

    __shared__ float tmp[C][W];   // 16 KiB, swizzled rows

    // ---- vertical combine -> swizzled LDS ----
    {
        const int v    = (cc4 >> 5) & 31;
        const int base = cc4 ^ (v & ~3);
        const int p    = v & 3;
        const bool q1 = (p & 1) != 0;
        const bool q2 = (p & 2) != 0;
#define COMB1(cc, a0, a1, a2, a3)                                          \
        {                                                                  \
            float e0 = wy0 * a0.x + wy1 * a1.x + wy2 * a2.x + wy3 * a3.x;  \
            float e1 = wy0 * a0.y + wy1 * a1.y + wy2 * a2.y + wy3 * a3.y;  \
            float e2 = wy0 * a0.z + wy1 * a1.z + wy2 * a2.z + wy3 * a3.z;  \
            float e3 = wy0 * a0.w + wy1 * a1.w + wy2 * a2.w + wy3 * a3.w;  \
            float t0 = q1 ? e1 : e0;                                       \
            float t1 = q1 ? e0 : e1;                                       \
            float t2 = q1 ? e3 : e2;                                       \
            float t3 = q1 ? e2 : e3;                                       \
            float u0 = q2 ? t2 : t0;                                       \
            float u1 = q2 ? t3 : t1;                                       \
            float u2 = q2 ? t0 : t2;                                       \
            float u3 = q2 ? t1 : t3;                                       \
            *(float4*)&tmp[cc][base] = make_float4(u0, u1, u2, u3);        \
        }
        COMB1(ch0 + 0, p00, p01, p02, p03);
        COMB1(ch0 + 2, p10, p11, p12, p13);
        COMB1(ch0 + 4, p20, p21, p22, p23);
        COMB1(ch0 + 6, p30, p31, p32, p33);
#undef COMB1
    }
    __syncthreads();

    // ---- horizontal pass: 4 LDS taps per output, NT float2 stores ----
    float* obase = out + ((size_t)b * C * H + h) * W + 2 * t;
    #pragma unroll
    for (int c = 0; c < C; ++c) {
        const float* tr = tmp[c];
        const float s0 = ta.w.x * tr[ta.i.x] + ta.w.y * tr[ta.i.y]
                       + ta.w.z * tr[ta.i.z] + ta.w.w * tr[ta.i.w];
        const float s1 = tb.w.x * tr[tb.i.x] + tb.w.y * tr[tb.i.y]
                       + tb.w.z * tr[tb.i.z] + tb.w.w * tr[tb.i.w];
        float2 v2 = make_float2(s0, s1);
        double dv;
        memcpy(&dv, &v2, 8);
        __builtin_nontemporal_store(dv, (double*)(obase + (size_t)c * (H * W)));
    }
}

// ---------------- fallback (inline taps, = round-5 kernel) ----------------
__global__ __launch_bounds__(256, 4)
void pds5_kernel(const float* __restrict__ x,
                 const float* __restrict__ rate,
                 const float* __restrict__ center,
                 float* __restrict__ out)
{
    constexpr int C = 8, H = 512, W = 512;
    const int orig = blockIdx.x;
    const int id = (orig & 7) * 1024 + (orig >> 3);
    const int b = id >> 9;
    const int h = id & (H - 1);
    const float r  = rate[b];
    const float cx = center[2 * b + 0];
    const float cy = center[2 * b + 1];
    const float inv_r = 1.0f / r;
    const int t = threadIdx.x;

    const float gy = 0.00390625f * (float)h - 1.0f;
    const float Gy = (gy - cy) * inv_r + cy;
    const float iy = (Gy + 1.0f) * 0.5f * 511.0f;
    const float y0 = floorf(iy);
    const float ty = iy - y0;
    const int   y0i = (int)y0;
    const float wy0 = k2f(ty + 1.0f);
    const float wy1 = k1f(ty);
    const float wy2 = k1f(1.0f - ty);
    const float wy3 = k2f(2.0f - ty);
    const int ro0 = reflect_clip(y0i - 1, H) * W;
    const int ro1 = reflect_clip(y0i    , H) * W;
    const int ro2 = reflect_clip(y0i + 1, H) * W;
    const int ro3 = reflect_clip(y0i + 2, H) * W;

    const float* imgb = x + (size_t)b * C * H * W;
    const int cc4 = (t & 127) << 2;
    const int ch0 = (t >> 7);
    const float* base0 = imgb + (size_t)(ch0 + 0) * (H * W) + cc4;
    const float* base1 = imgb + (size_t)(ch0 + 2) * (H * W) + cc4;
    const float* base2 = imgb + (size_t)(ch0 + 4) * (H * W) + cc4;
    const float* base3 = imgb + (size_t)(ch0 + 6) * (H * W) + cc4;

    float4 p00 = *(const float4*)(base0 + ro0);
    float4 p01 = *(const float4*)(base0 + ro1);
    float4 p02 = *(const float4*)(base0 + ro2);
    float4 p03 = *(const float4*)(base0 + ro3);
    float4 p10 = *(const float4*)(base1 + ro0);
    float4 p11 = *(const float4*)(base1 + ro1);
    float4 p12 = *(const float4*)(base1 + ro2);
    float4 p13 = *(const float4*)(base1 + ro3);
    float4 p20 = *(const float4*)(base2 + ro0);
    float4 p21 = *(const float4*)(base2 + ro1);
    float4 p22 = *(const float4*)(base2 + ro2);
    float4 p23 = *(const float4*)(base2 + ro3);
    float4 p30 = *(const float4*)(base3 + ro0);
    float4 p31 = *(const float4*)(base3 + ro1);
    float4 p32 = *(const float4*)(base3 + ro2);
    float4 p33 = *(const float4*)(base3 + ro3);
    asm volatile("" ::: "memory");

    int   sA0, sA1, sA2, sA3, sB0, sB1, sB2, sB3;
    float wxA0, wxA1, wxA2, wxA3, wxB0, wxB1, wxB2, wxB3;
    {
        const int w = 2 * t;
        const float gx = 0.00390625f * (float)w - 1.0f;
        const float Gx = (gx - cx) * inv_r + cx;
        const float ix = (Gx + 1.0f) * 0.5f * 511.0f;
        const float x0 = floorf(ix);
        const float tx = ix - x0;
        const int x0i = (int)x0;
        wxA0 = k2f(tx + 1.0f); wxA1 = k1f(tx);
        wxA2 = k1f(1.0f - tx); wxA3 = k2f(2.0f - tx);
        sA0 = swz(reflect_clip(x0i - 1, W)); sA1 = swz(reflect_clip(x0i,     W));
        sA2 = swz(reflect_clip(x0i + 1, W)); sA3 = swz(reflect_clip(x0i + 2, W));
    }
    {
        const int w = 2 * t + 1;
        const float gx = 0.00390625f * (float)w - 1.0f;
        const float Gx = (gx - cx) * inv_r + cx;
        const float ix = (Gx + 1.0f) * 0.5f * 511.0f;
        const float x0 = floorf(ix);
        const float tx = ix - x0;
        const int x0i = (int)x0;
        wxB0 = k2f(tx + 1.0f); wxB1 = k1f(tx);
        wxB2 = k1f(1.0f - tx); wxB3 = k2f(2.0f - tx);
        sB0 = swz(reflect_clip(x0i - 1, W)); sB1 = swz(reflect_clip(x0i,     W));
        sB2 = swz(reflect_clip(x0i + 1, W)); sB3 = swz(reflect_clip(x0i + 2, W));
    }

    __shared__ float tmp[C][W];
    {
        const int v    = (cc4 >> 5) & 31;
        const int base = cc4 ^ (v & ~3);
        const int p    = v & 3;
        const bool q1 = (p & 1) != 0;
        const bool q2 = (p & 2) != 0;
#define COMB1(cc, a0, a1, a2, a3)                                          \
        {                                                                  \
            float e0 = wy0 * a0.x + wy1 * a1.x + wy2 * a2.x + wy3 * a3.x;  \
            float e1 = wy0 * a0.y + wy1 * a1.y + wy2 * a2.y + wy3 * a3.y;  \
            float e2 = wy0 * a0.z + wy1 * a1.z + wy2 * a2.z + wy3 * a3.z;  \
            float e3 = wy0 * a0.w + wy1 * a1.w + wy2 * a2.w + wy3 * a3.w;  \
            float t0 = q1 ? e1 : e0;                                       \
            float t1 = q1 ? e0 : e1;                                       \
            float t2 = q1 ? e3 : e2;                                       \
            float t3 = q1 ? e2 : e3;                                       \
            float u0 = q2 ? t2 : t0;                                       \
            float u1 = q2 ? t3 : t1;                                       \
            float u2 = q2 ? t0 : t2;                                       \
            float u3 = q2 ? t1 : t3;                                       \
            *(float4*)&tmp[cc][base] = make_float4(u0, u1, u2, u3);        \
        }
        COMB1(ch0 + 0, p00, p01, p02, p03);
        COMB1(ch0 + 2, p10, p11, p12, p13);
        COMB1(ch0 + 4, p20, p21, p22, p23);
        COMB1(ch0 + 6, p30, p31, p32, p33);
#undef COMB1
    }
    __syncthreads();

    float* obase = out + ((size_t)b * C * H + h) * W + 2 * t;
    #pragma unroll
    for (int c = 0; c < C; ++c) {
        const float* tr = tmp[c];
        const float s0 = wxA0 * tr[sA0] + wxA1 * tr[sA1]
                       + wxA2 * tr[sA2] + wxA3 * tr[sA3];
        const float s1 = wxB0 * tr[sB0] + wxB1 * tr[sB1]
                       + wxB2 * tr[sB2] + wxB3 * tr[sB3];
        float2 v2 = make_float2(s0, s1);
        double dv;
        memcpy(&dv, &v2, 8);
        __builtin_nontemporal_store(dv, (double*)(obase + (size_t)c * (H * W)));
    }
}

extern "C" void kernel_launch(void* const* d_in, const int* in_sizes, int n_in,
                              void* d_out, int out_size, void* d_ws, size_t ws_size,
                              hipStream_t stream) {
    const float* x      = (const float*)d_in[0];
    const float* rate   = (const float*)d_in[1];
    const float* center = (const float*)d_in[2];
    float* out          = (float*)d_out;

    constexpr int B = 16, H = 512;
    const size_t TAB = (size_t)8192 * sizeof(Tap);   // 256 KB each

    if (ws_size >= 2 * TAB) {
        Tap* ytab = (Tap*)d_ws;
        Tap* xtab = (Tap*)((char*)d_ws + TAB);
        tap_kernel<<<64, 256, 0, stream>>>(rate, center, ytab, xtab);
        pds6_kernel<<<B * H, 256, 0, stream>>>(x, ytab, xtab, out);
    } else {
        pds5_kernel<<<B * H, 256, 0, stream>>>(x, rate, center, out);
    }
}

// Round 7
// 57.457 us; speedup vs baseline: 1.0884x; 1.0884x over previous
//
#include <hip/hip_runtime.h>

#define AA (-0.75f)

__device__ __forceinline__ float k1f(float x) {
    return ((AA + 2.0f) * x - (AA + 3.0f)) * x * x + 1.0f;
}
__device__ __forceinline__ float k2f(float x) {
    return ((AA * x - 5.0f * AA) * x + 8.0f * AA) * x - 4.0f * AA;
}

__device__ __forceinline__ int reflect_clip(int idx, int size) {
    int span = size - 1;
    int i = idx < 0 ? -idx : idx;
    i = i % (2 * span);
    if (i > span) i = 2 * span - i;
    return i;
}

// LDS bank swizzle: logical element a -> a ^ ((a>>5)&31). Bijective per row.
__device__ __forceinline__ int swz(int a) { return a ^ ((a >> 5) & 31); }

typedef float f32x4 __attribute__((ext_vector_type(4)));

// Separable bicubic. 128-thread block per (b, h, 4-channel half):
// 8 KiB LDS/block -> up to 16 resident blocks/CU so independent blocks'
// load phases overlap (HBM fed continuously). y-taps inline (short SALU/VALU
// chain, no load dependency) -> issue all 16 float4 loads -> x-tap VALU under
// load shadow -> combine -> swizzled LDS -> horizontal 4-tap -> NT float4 store.
__global__ __launch_bounds__(128, 6)
void pds7_kernel(const float* __restrict__ x,
                 const float* __restrict__ rate,
                 const float* __restrict__ center,
                 float* __restrict__ out)
{
    constexpr int C = 8, H = 512, W = 512, HW = H * W;

    // XCD-chunked remap (16384 % 8 == 0 -> bijective). id = b*1024 + h*2 + half:
    // consecutive ids on one XCD are h-adjacent -> tap-row L2 reuse.
    const int orig = blockIdx.x;
    const int id   = (orig & 7) * 2048 + (orig >> 3);
    const int b    = id >> 10;
    const int rem  = id & 1023;
    const int h    = rem >> 1;
    const int half = rem & 1;
    const int ch0  = half * 4;
    const int t    = threadIdx.x;

    const float r  = rate[b];
    const float cx = center[2 * b + 0];
    const float cy = center[2 * b + 1];
    const float inv_r = 1.0f / r;

    // ---- y taps (uniform, short chain — keep OFF the load path) ----
    const float gy = 0.00390625f * (float)h - 1.0f;
    const float Gy = (gy - cy) * inv_r + cy;
    const float iy = (Gy + 1.0f) * 0.5f * 511.0f;
    const float y0 = floorf(iy);
    const float ty = iy - y0;
    const int   y0i = (int)y0;
    const float wy0 = k2f(ty + 1.0f);
    const float wy1 = k1f(ty);
    const float wy2 = k1f(1.0f - ty);
    const float wy3 = k2f(2.0f - ty);
    const int ro0 = reflect_clip(y0i - 1, H) * W;
    const int ro1 = reflect_clip(y0i    , H) * W;
    const int ro2 = reflect_clip(y0i + 1, H) * W;
    const int ro3 = reflect_clip(y0i + 2, H) * W;

    // ---- issue all 16 row loads (4 channels x 4 row-taps) ----
    const float* imgb = x + (size_t)b * C * HW;
    const int cc4 = t << 2;                       // 16B-aligned group, 0..508
    const float* base0 = imgb + (size_t)(ch0 + 0) * HW + cc4;
    const float* base1 = imgb + (size_t)(ch0 + 1) * HW + cc4;
    const float* base2 = imgb + (size_t)(ch0 + 2) * HW + cc4;
    const float* base3 = imgb + (size_t)(ch0 + 3) * HW + cc4;

    float4 p00 = *(const float4*)(base0 + ro0);
    float4 p01 = *(const float4*)(base0 + ro1);
    float4 p02 = *(const float4*)(base0 + ro2);
    float4 p03 = *(const float4*)(base0 + ro3);
    float4 p10 = *(const float4*)(base1 + ro0);
    float4 p11 = *(const float4*)(base1 + ro1);
    float4 p12 = *(const float4*)(base1 + ro2);
    float4 p13 = *(const float4*)(base1 + ro3);
    float4 p20 = *(const float4*)(base2 + ro0);
    float4 p21 = *(const float4*)(base2 + ro1);
    float4 p22 = *(const float4*)(base2 + ro2);
    float4 p23 = *(const float4*)(base2 + ro3);
    float4 p30 = *(const float4*)(base3 + ro0);
    float4 p31 = *(const float4*)(base3 + ro1);
    float4 p32 = *(const float4*)(base3 + ro2);
    float4 p33 = *(const float4*)(base3 + ro3);
    asm volatile("" ::: "memory");   // loads may not sink below this point

    // ---- x taps for cols 4t+0..4t+3 (VALU under load shadow) ----
    int   s00,s01,s02,s03, s10,s11,s12,s13, s20,s21,s22,s23, s30,s31,s32,s33;
    float w00,w01,w02,w03, w10,w11,w12,w13, w20,w21,w22,w23, w30,w31,w32,w33;
#define XTAP(wcol, S0,S1,S2,S3, W0,W1,W2,W3)                               \
    {                                                                      \
        const float gx = 0.00390625f * (float)(wcol) - 1.0f;               \
        const float Gx = (gx - cx) * inv_r + cx;                           \
        const float ix = (Gx + 1.0f) * 0.5f * 511.0f;                      \
        const float x0 = floorf(ix);                                       \
        const float tx = ix - x0;                                          \
        const int x0i = (int)x0;                                           \
        W0 = k2f(tx + 1.0f); W1 = k1f(tx);                                 \
        W2 = k1f(1.0f - tx); W3 = k2f(2.0f - tx);                          \
        S0 = swz(reflect_clip(x0i - 1, W)); S1 = swz(reflect_clip(x0i,     W)); \
        S2 = swz(reflect_clip(x0i + 1, W)); S3 = swz(reflect_clip(x0i + 2, W)); \
    }
    XTAP(4 * t + 0, s00,s01,s02,s03, w00,w01,w02,w03);
    XTAP(4 * t + 1, s10,s11,s12,s13, w10,w11,w12,w13);
    XTAP(4 * t + 2, s20,s21,s22,s23, w20,w21,w22,w23);
    XTAP(4 * t + 3, s30,s31,s32,s33, w30,w31,w32,w33);
#undef XTAP

    __shared__ float tmp[4][W];   // 8 KiB, swizzled rows

    // ---- vertical combine -> swizzled LDS ----
    {
        const int v    = (cc4 >> 5) & 31;
        const int base = cc4 ^ (v & ~3);
        const int p    = v & 3;
        const bool q1 = (p & 1) != 0;
        const bool q2 = (p & 2) != 0;
#define COMB1(k, a0, a1, a2, a3)                                           \
        {                                                                  \
            float e0 = wy0 * a0.x + wy1 * a1.x + wy2 * a2.x + wy3 * a3.x;  \
            float e1 = wy0 * a0.y + wy1 * a1.y + wy2 * a2.y + wy3 * a3.y;  \
            float e2 = wy0 * a0.z + wy1 * a1.z + wy2 * a2.z + wy3 * a3.z;  \
            float e3 = wy0 * a0.w + wy1 * a1.w + wy2 * a2.w + wy3 * a3.w;  \
            float t0 = q1 ? e1 : e0;                                       \
            float t1 = q1 ? e0 : e1;                                       \
            float t2 = q1 ? e3 : e2;                                       \
            float t3 = q1 ? e2 : e3;                                       \
            float u0 = q2 ? t2 : t0;                                       \
            float u1 = q2 ? t3 : t1;                                       \
            float u2 = q2 ? t0 : t2;                                       \
            float u3 = q2 ? t1 : t3;                                       \
            *(float4*)&tmp[k][base] = make_float4(u0, u1, u2, u3);         \
        }
        COMB1(0, p00, p01, p02, p03);
        COMB1(1, p10, p11, p12, p13);
        COMB1(2, p20, p21, p22, p23);
        COMB1(3, p30, p31, p32, p33);
#undef COMB1
    }
    __syncthreads();

    // ---- horizontal pass: 4 cols x 4 channels, NT float4 stores ----
    float* ob = out + (((size_t)(b * C + ch0)) * H + h) * W + (t << 2);
    #pragma unroll
    for (int c = 0; c < 4; ++c) {
        const float* tr = tmp[c];
        const float o0 = w00 * tr[s00] + w01 * tr[s01] + w02 * tr[s02] + w03 * tr[s03];
        const float o1 = w10 * tr[s10] + w11 * tr[s11] + w12 * tr[s12] + w13 * tr[s13];
        const float o2 = w20 * tr[s20] + w21 * tr[s21] + w22 * tr[s22] + w23 * tr[s23];
        const float o3 = w30 * tr[s30] + w31 * tr[s31] + w32 * tr[s32] + w33 * tr[s33];
        f32x4 v = {o0, o1, o2, o3};
        __builtin_nontemporal_store(v, (f32x4*)(ob + (size_t)c * HW));
    }
}

extern "C" void kernel_launch(void* const* d_in, const int* in_sizes, int n_in,
                              void* d_out, int out_size, void* d_ws, size_t ws_size,
                              hipStream_t stream) {
    const float* x      = (const float*)d_in[0];
    const float* rate   = (const float*)d_in[1];
    const float* center = (const float*)d_in[2];
    float* out          = (float*)d_out;

    constexpr int B = 16, H = 512;
    dim3 grid(B * H * 2);     // (b, h, channel-half)
    dim3 block(128);
    pds7_kernel<<<grid, block, 0, stream>>>(x, rate, center, out);
}

// Round 8
// 57.085 us; speedup vs baseline: 1.0955x; 1.0065x over previous
//
#include <hip/hip_runtime.h>
#include <string.h>

#define AA (-0.75f)

__device__ __forceinline__ float k1f(float x) {
    return ((AA + 2.0f) * x - (AA + 3.0f)) * x * x + 1.0f;
}
__device__ __forceinline__ float k2f(float x) {
    return ((AA * x - 5.0f * AA) * x + 8.0f * AA) * x - 4.0f * AA;
}

__device__ __forceinline__ int reflect_clip(int idx, int size) {
    int span = size - 1;
    int i = idx < 0 ? -idx : idx;
    i = i % (2 * span);
    if (i > span) i = 2 * span - i;
    return i;
}

// LDS bank swizzle: logical element a -> a ^ ((a>>5)&31). Bijective per row.
__device__ __forceinline__ int swz(int a) { return a ^ ((a >> 5) & 31); }

typedef float f32x4 __attribute__((ext_vector_type(4)));

// Separable bicubic, one block per (b,h), 256 threads.
// Key change vs R5: sched_barrier(0) after the 16 loads. The old "memory"
// clobber let LLVM hoist the (register-only) combine FMAs up between the
// loads (VGPR=32 proved it), serializing phase 1 into load->use pairs.
// sched_barrier(0) pins all 16 loads above as one burst (true 16-deep MLP,
// results live across the barrier), x-tap VALU runs after issue, waits land
// only at the combine uses.
__global__ __launch_bounds__(256, 4)
void pds8_kernel(const float* __restrict__ x,
                 const float* __restrict__ rate,
                 const float* __restrict__ center,
                 float* __restrict__ out)
{
    constexpr int C = 8, H = 512, W = 512, HW = H * W;

    // XCD-chunked remap (8192 % 8 == 0 -> bijective): same-XCD blocks get
    // consecutive (b,h) -> tap-row L2 reuse.
    const int orig = blockIdx.x;
    const int id = (orig & 7) * 1024 + (orig >> 3);
    const int b = id >> 9;
    const int h = id & (H - 1);

    const float r  = rate[b];
    const float cx = center[2 * b + 0];
    const float cy = center[2 * b + 1];
    const float inv_r = 1.0f / r;
    const int t = threadIdx.x;

    // ---- y taps (block-uniform, short chain) ----
    const float gy = 0.00390625f * (float)h - 1.0f;
    const float Gy = (gy - cy) * inv_r + cy;
    const float iy = (Gy + 1.0f) * 0.5f * 511.0f;
    const float y0 = floorf(iy);
    const float ty = iy - y0;
    const int   y0i = (int)y0;
    const float wy0 = k2f(ty + 1.0f);
    const float wy1 = k1f(ty);
    const float wy2 = k1f(1.0f - ty);
    const float wy3 = k2f(2.0f - ty);
    const int ro0 = reflect_clip(y0i - 1, H) * W;
    const int ro1 = reflect_clip(y0i    , H) * W;
    const int ro2 = reflect_clip(y0i + 1, H) * W;
    const int ro3 = reflect_clip(y0i + 2, H) * W;

    // ---- issue ALL 16 phase-1 loads as one burst ----
    const float* imgb = x + (size_t)b * C * HW;
    const int cc4 = (t & 127) << 2;           // 16B-aligned group in row
    const int ch0 = (t >> 7);                 // 0 or 1
    const float* base0 = imgb + (size_t)(ch0 + 0) * HW + cc4;
    const float* base1 = imgb + (size_t)(ch0 + 2) * HW + cc4;
    const float* base2 = imgb + (size_t)(ch0 + 4) * HW + cc4;
    const float* base3 = imgb + (size_t)(ch0 + 6) * HW + cc4;

    f32x4 p00 = *(const f32x4*)(base0 + ro0);
    f32x4 p01 = *(const f32x4*)(base0 + ro1);
    f32x4 p02 = *(const f32x4*)(base0 + ro2);
    f32x4 p03 = *(const f32x4*)(base0 + ro3);
    f32x4 p10 = *(const f32x4*)(base1 + ro0);
    f32x4 p11 = *(const f32x4*)(base1 + ro1);
    f32x4 p12 = *(const f32x4*)(base1 + ro2);
    f32x4 p13 = *(const f32x4*)(base1 + ro3);
    f32x4 p20 = *(const f32x4*)(base2 + ro0);
    f32x4 p21 = *(const f32x4*)(base2 + ro1);
    f32x4 p22 = *(const f32x4*)(base2 + ro2);
    f32x4 p23 = *(const f32x4*)(base2 + ro3);
    f32x4 p30 = *(const f32x4*)(base3 + ro0);
    f32x4 p31 = *(const f32x4*)(base3 + ro1);
    f32x4 p32 = *(const f32x4*)(base3 + ro2);
    f32x4 p33 = *(const f32x4*)(base3 + ro3);
    // NOTHING may cross this point: loads pinned above (one 16-deep burst),
    // all arithmetic pinned below.
    __builtin_amdgcn_sched_barrier(0);

    // ---- x taps for cols 2t, 2t+1 (VALU after load issue, before waits) ----
    int   sA0, sA1, sA2, sA3, sB0, sB1, sB2, sB3;
    float wxA0, wxA1, wxA2, wxA3, wxB0, wxB1, wxB2, wxB3;
    {
        const int w = 2 * t;
        const float gx = 0.00390625f * (float)w - 1.0f;
        const float Gx = (gx - cx) * inv_r + cx;
        const float ix = (Gx + 1.0f) * 0.5f * 511.0f;
        const float x0 = floorf(ix);
        const float tx = ix - x0;
        const int x0i = (int)x0;
        wxA0 = k2f(tx + 1.0f); wxA1 = k1f(tx);
        wxA2 = k1f(1.0f - tx); wxA3 = k2f(2.0f - tx);
        sA0 = swz(reflect_clip(x0i - 1, W)); sA1 = swz(reflect_clip(x0i,     W));
        sA2 = swz(reflect_clip(x0i + 1, W)); sA3 = swz(reflect_clip(x0i + 2, W));
    }
    {
        const int w = 2 * t + 1;
        const float gx = 0.00390625f * (float)w - 1.0f;
        const float Gx = (gx - cx) * inv_r + cx;
        const float ix = (Gx + 1.0f) * 0.5f * 511.0f;
        const float x0 = floorf(ix);
        const float tx = ix - x0;
        const int x0i = (int)x0;
        wxB0 = k2f(tx + 1.0f); wxB1 = k1f(tx);
        wxB2 = k1f(1.0f - tx); wxB3 = k2f(2.0f - tx);
        sB0 = swz(reflect_clip(x0i - 1, W)); sB1 = swz(reflect_clip(x0i,     W));
        sB2 = swz(reflect_clip(x0i + 1, W)); sB3 = swz(reflect_clip(x0i + 2, W));
    }

    __shared__ float tmp[C][W];   // 16 KiB, swizzled rows

    // ---- vertical combine -> swizzled LDS ----
    {
        const int v    = (cc4 >> 5) & 31;
        const int base = cc4 ^ (v & ~3);
        const int p    = v & 3;
        const bool q1 = (p & 1) != 0;
        const bool q2 = (p & 2) != 0;
#define COMB1(cc, a0, a1, a2, a3)                                          \
        {                                                                  \
            float e0 = wy0 * a0.x + wy1 * a1.x + wy2 * a2.x + wy3 * a3.x;  \
            float e1 = wy0 * a0.y + wy1 * a1.y + wy2 * a2.y + wy3 * a3.y;  \
            float e2 = wy0 * a0.z + wy1 * a1.z + wy2 * a2.z + wy3 * a3.z;  \
            float e3 = wy0 * a0.w + wy1 * a1.w + wy2 * a2.w + wy3 * a3.w;  \
            float t0 = q1 ? e1 : e0;                                       \
            float t1 = q1 ? e0 : e1;                                       \
            float t2 = q1 ? e3 : e2;                                       \
            float t3 = q1 ? e2 : e3;                                       \
            float u0 = q2 ? t2 : t0;                                       \
            float u1 = q2 ? t3 : t1;                                       \
            float u2 = q2 ? t0 : t2;                                       \
            float u3 = q2 ? t1 : t3;                                       \
            *(float4*)&tmp[cc][base] = make_float4(u0, u1, u2, u3);        \
        }
        COMB1(ch0 + 0, p00, p01, p02, p03);
        COMB1(ch0 + 2, p10, p11, p12, p13);
        COMB1(ch0 + 4, p20, p21, p22, p23);
        COMB1(ch0 + 6, p30, p31, p32, p33);
#undef COMB1
    }
    __syncthreads();

    // ---- horizontal pass: 4 LDS taps per output, NT float2 stores ----
    float* obase = out + ((size_t)b * C * H + h) * W + 2 * t;
    #pragma unroll
    for (int c = 0; c < C; ++c) {
        const float* tr = tmp[c];
        const float s0 = wxA0 * tr[sA0] + wxA1 * tr[sA1]
                       + wxA2 * tr[sA2] + wxA3 * tr[sA3];
        const float s1 = wxB0 * tr[sB0] + wxB1 * tr[sB1]
                       + wxB2 * tr[sB2] + wxB3 * tr[sB3];
        float2 v2 = make_float2(s0, s1);
        double dv;
        memcpy(&dv, &v2, 8);
        __builtin_nontemporal_store(dv, (double*)(obase + (size_t)c * HW));
    }
}

extern "C" void kernel_launch(void* const* d_in, const int* in_sizes, int n_in,
                              void* d_out, int out_size, void* d_ws, size_t ws_size,
                              hipStream_t stream) {
    const float* x      = (const float*)d_in[0];
    const float* rate   = (const float*)d_in[1];
    const float* center = (const float*)d_in[2];
    float* out          = (float*)d_out;

    constexpr int B = 16, H = 512;
    dim3 grid(B * H);
    dim3 block(256);
    pds8_kernel<<<grid, block, 0, stream>>>(x, rate, center, out);
}